// Round 17
// baseline (72.759 us; speedup 1.0000x reference)
//
#include <hip/hip_runtime.h>

// GBDT ensemble inference — R17: R15 pipeline with ASM-EMITTED gathers.
// global_load_dwordx4 via asm volatile cannot be re-serialized by the
// scheduler: all 16 PT2 loads go in flight together, one s_waitcnt vmcnt(0)
// + sched_barrier(0), then all 16 PT3 loads likewise. Exposed VMEM waits
// per wave: ~16 -> 2. B=32768, T=512, D=8, F=512, C=1.
//
// ws16 layout (int4 records):
//   PT0 [0,1024):      levels 0,1   (staged to LDS)
//   PT1 [1024,5120):   levels 2,3   (staged to LDS)
//   PT2 [5120,21504):  levels 4,5   (VMEM, asm-pipelined)
//   PT3 [21504,87040): level 6+leaf (VMEM, asm-pipelined)
// Pair rec: {f0|fL<<10|fR<<20, b0, bL, bR}; PT3 rec: {f6, b6, leafL, leafR}.
//
// Mapping: lane = row (0..31) + tree-group g (lane>>5); wave owns 32 trees;
// lane owns 4 consecutive trees in each of 4 steps; float4 leaf stores.
// LDS: xs(66KB) + pt0(16KB) + pt1(64KB) + rt(4KB) = 152 KB, 1 block/CU.

#define BB 32768
#define TT 512
#define FF 512
#define PADW 65536
#define ROWS 32
#define THREADS 1024
#define TPW 32
#define XSS 515           // odd stride: correlated-feature lanes spread banks

#define PT0_OFF 0
#define PT1_OFF 1024
#define PT2_OFF 5120
#define PT3_OFF 21504
#define N_REC   87040

typedef int i32x4 __attribute__((ext_vector_type(4)));

// Volatile asm gather: cannot be sunk/re-serialized by the scheduler.
#define GLOAD16(DST, PTR)                                                     \
    asm volatile("global_load_dwordx4 %0, %1, off"                            \
                 : "=&v"(DST) : "v"((unsigned long long)(PTR)))

__global__ __launch_bounds__(256) void build_tables_kernel(
    const int*   __restrict__ nodes_lv,
    const float* __restrict__ biases_lv,
    const float* __restrict__ leaf_nodes,
    int4*        __restrict__ ws16)
{
    const int i = blockIdx.x * 256 + threadIdx.x;
    if (i >= N_REC) return;

    int l, p, off;
    if (i < PT1_OFF)      { l = 0; off = PT0_OFF; }
    else if (i < PT2_OFF) { l = 2; off = PT1_OFF; }
    else if (i < PT3_OFF) { l = 4; off = PT2_OFF; }
    else {
        p = i - PT3_OFF;
        const int   f  = nodes_lv[6 * PADW + p];
        const float b  = biases_lv[6 * PADW + p];
        const float lL = leaf_nodes[2 * p];
        const float lR = leaf_nodes[2 * p + 1];
        ws16[i] = make_int4(f, __float_as_int(b),
                            __float_as_int(lL), __float_as_int(lR));
        return;
    }
    p = i - off;
    const int   f0 = nodes_lv[l * PADW + p];
    const float b0 = biases_lv[l * PADW + p];
    const int   fL = nodes_lv[(l + 1) * PADW + 2 * p];
    const int   fR = nodes_lv[(l + 1) * PADW + 2 * p + 1];
    const float bL = biases_lv[(l + 1) * PADW + 2 * p];
    const float bR = biases_lv[(l + 1) * PADW + 2 * p + 1];
    ws16[i] = make_int4(f0 | (fL << 10) | (fR << 20), __float_as_int(b0),
                        __float_as_int(bL), __float_as_int(bR));
}

// Serial 2-level resolve on an i32x4 record
#define PAIR_RESOLVE(REC, P)                                                  \
    {                                                                         \
        const int   fp = (REC).x;                                             \
        const bool  g0 = xrow[fp & 1023] >= __int_as_float((REC).y);          \
        const int   f1 = g0 ? ((fp >> 20) & 1023) : ((fp >> 10) & 1023);      \
        const float h1 = g0 ? __int_as_float((REC).w) : __int_as_float((REC).z); \
        const bool  g1 = xrow[f1] >= h1;                                      \
        (P) = 4 * (P) + 2 * (int)g0 + (int)g1;                                \
    }

__global__ __launch_bounds__(THREADS, 4) void gbdt_walk_kernel(
    const float* __restrict__ x,
    const int*   __restrict__ root_nodes,
    const float* __restrict__ root_biases,
    const int4*  __restrict__ ws16,
    float*       __restrict__ out)
{
    __shared__ float xs[ROWS * XSS];   // 65,920 B
    __shared__ int4  pt0[1024];        // 16,384 B (levels 0,1)
    __shared__ int4  pt1[4096];        // 65,536 B (levels 2,3)
    __shared__ int2  rt[512];          //  4,096 B (root f,b)   total 151,936 B

    const int tid = threadIdx.x;
    const int b0  = blockIdx.x * ROWS;

    // ---- stage x rows (coalesced float4) ----
    const float4* __restrict__ xr = (const float4*)(x + (size_t)b0 * FF);
    #pragma unroll
    for (int i = 0; i < (ROWS * FF / 4) / THREADS; ++i) {   // 4 iters
        int fidx = i * THREADS + tid;
        int r = fidx >> 7, c4 = fidx & 127;
        float4 v = xr[fidx];
        float* d = &xs[r * XSS + (c4 << 2)];
        d[0] = v.x; d[1] = v.y; d[2] = v.z; d[3] = v.w;
    }
    // ---- stage PT0+PT1 (5120 int4, coalesced) ----
    #pragma unroll
    for (int i = 0; i < 5; ++i) {
        int idx = i * THREADS + tid;
        if (idx < 5120) {
            int4 v = ws16[idx];
            if (idx < 1024) pt0[idx] = v;
            else            pt1[idx - 1024] = v;
        }
    }
    // ---- stage roots ----
    if (tid < 512)
        rt[tid] = make_int2(root_nodes[tid], __float_as_int(root_biases[tid]));
    __syncthreads();

    const int wv   = tid >> 6;              // wave 0..15
    const int lane = tid & 63;
    const int row  = lane & 31;
    const int g    = lane >> 5;
    const int tb   = wv * TPW;
    const float* __restrict__ xrow = &xs[row * XSS];
    float* __restrict__ orow = out + (size_t)(b0 + row) * TT;

    int   p4[16];
    i32x4 r2[16];

    // ---- Pass 1: LDS levels 0-3 per chain, asm-issue PT2 gather ----
    #pragma unroll
    for (int s = 0; s < 4; ++s) {
        const int tbase = tb + 8 * s + 4 * g;
        #pragma unroll
        for (int c = 0; c < 4; ++c) {
            const int t = tbase + c;
            const int2 rn = rt[t];
            int p = 2 * t + (xrow[rn.x] >= __int_as_float(rn.y) ? 1 : 0);
            const int4 q0 = pt0[p];
            { const i32x4 r0 = { q0.x, q0.y, q0.z, q0.w }; PAIR_RESOLVE(r0, p); }
            const int4 q1 = pt1[p];
            { const i32x4 r1 = { q1.x, q1.y, q1.z, q1.w }; PAIR_RESOLVE(r1, p); }
            p4[4 * s + c] = p;
            GLOAD16(r2[4 * s + c], ws16 + PT2_OFF + p);   // in flight, no wait
        }
    }
    asm volatile("s_waitcnt vmcnt(0)" ::: "memory");
    __builtin_amdgcn_sched_barrier(0);

    // ---- Pass 2: resolve PT2, asm-issue PT3 ----
    i32x4 r3[16];
    #pragma unroll
    for (int i = 0; i < 16; ++i) {
        int p = p4[i];
        PAIR_RESOLVE(r2[i], p);
        GLOAD16(r3[i], ws16 + PT3_OFF + p);
    }
    asm volatile("s_waitcnt vmcnt(0)" ::: "memory");
    __builtin_amdgcn_sched_barrier(0);

    // ---- Pass 3: resolve PT3 -> leaf stores ----
    #pragma unroll
    for (int s = 0; s < 4; ++s) {
        const int tbase = tb + 8 * s + 4 * g;
        float v[4];
        #pragma unroll
        for (int c = 0; c < 4; ++c) {
            const i32x4 r = r3[4 * s + c];
            const bool gg = xrow[r.x] >= __int_as_float(r.y);
            v[c] = gg ? __int_as_float(r.w) : __int_as_float(r.z);
        }
        *(float4*)&orow[tbase] = make_float4(v[0], v[1], v[2], v[3]);
    }
}

// Fallback (ws too small): direct gathers from the original tables.
__global__ __launch_bounds__(THREADS) void gbdt_walk_fallback(
    const float* __restrict__ x,
    const int*   __restrict__ root_nodes,
    const float* __restrict__ root_biases,
    const int*   __restrict__ nodes_lv,
    const float* __restrict__ biases_lv,
    const float* __restrict__ leaf_nodes,
    float*       __restrict__ out)
{
    __shared__ float xs[ROWS * XSS];
    const int tid = threadIdx.x;
    const int b0  = blockIdx.x * ROWS;
    const float4* __restrict__ xr = (const float4*)(x + (size_t)b0 * FF);
    #pragma unroll
    for (int i = 0; i < (ROWS * FF / 4) / THREADS; ++i) {
        int fidx = i * THREADS + tid;
        int r = fidx >> 7, c4 = fidx & 127;
        float4 v = xr[fidx];
        float* d = &xs[r * XSS + (c4 << 2)];
        d[0] = v.x; d[1] = v.y; d[2] = v.z; d[3] = v.w;
    }
    __syncthreads();
    const int wv   = tid >> 6;
    const int lane = tid & 63;
    const int row  = lane & 31;
    const int g    = lane >> 5;
    const int tb   = wv * TPW;
    const float* __restrict__ xrow = &xs[row * XSS];
    float* __restrict__ orow = out + (size_t)(b0 + row) * TT;
    #pragma unroll
    for (int s = 0; s < TPW / 2; ++s) {
        const int t = tb + 2 * s + g;
        int p = 2 * t + (xrow[root_nodes[t]] >= root_biases[t] ? 1 : 0);
        #pragma unroll
        for (int l = 0; l < 7; ++l) {
            const int   f = nodes_lv[l * PADW + p];
            const float h = biases_lv[l * PADW + p];
            p = 2 * p + (xrow[f] >= h ? 1 : 0);
        }
        orow[t] = leaf_nodes[p];
    }
}

extern "C" void kernel_launch(void* const* d_in, const int* in_sizes, int n_in,
                              void* d_out, int out_size, void* d_ws, size_t ws_size,
                              hipStream_t stream) {
    const float* x            = (const float*)d_in[0];
    const int*   root_nodes   = (const int*)  d_in[1];
    const float* root_biases  = (const float*)d_in[2];
    const int*   nodes_lv     = (const int*)  d_in[4];
    const float* biases_lv    = (const float*)d_in[5];
    const float* leaf_nodes   = (const float*)d_in[6];
    float*       out          = (float*)d_out;

    dim3 grid(BB / ROWS);   // 1024 blocks
    dim3 block(THREADS);

    if (ws_size >= (size_t)N_REC * 16) {
        int4* ws16 = (int4*)d_ws;
        build_tables_kernel<<<(N_REC + 255) / 256, 256, 0, stream>>>(
            nodes_lv, biases_lv, leaf_nodes, ws16);
        gbdt_walk_kernel<<<grid, block, 0, stream>>>(
            x, root_nodes, root_biases, ws16, out);
    } else {
        gbdt_walk_fallback<<<grid, block, 0, stream>>>(
            x, root_nodes, root_biases, nodes_lv, biases_lv, leaf_nodes, out);
    }
}

// Round 18
// 72.151 us; speedup vs baseline: 1.0084x; 1.0084x over previous
//
#include <hip/hip_runtime.h>

// GBDT ensemble inference — R18: forced 2x8-chain VMEM pipeline with NAMED
// registers (no arrays -> no scratch, rule #20) and counted vmcnt (T4).
// Issue A.PT2x8 -> B LDS pass + B.PT2x8 -> vmcnt(8) -> resolve A + A.PT3x8
// -> vmcnt(8) -> resolve B + B.PT3x8 -> vmcnt(8) -> A stores -> vmcnt(2)
// -> B stores. Exposed waits ~16 -> 4, each pre-hidden.
// B=32768, T=512, D=8, F=512, C=1.
//
// ws16 layout (int4 records):
//   PT0 [0,1024):      levels 0,1   (staged to LDS)
//   PT1 [1024,5120):   levels 2,3   (staged to LDS)
//   PT2 [5120,21504):  levels 4,5   (VMEM, asm-pipelined)
//   PT3 [21504,87040): level 6+leaf (VMEM, asm-pipelined)
// Pair rec: {f0|fL<<10|fR<<20, b0, bL, bR}; PT3 rec: {f6, b6, leafL, leafR}.
//
// Mapping: lane = row (0..31) + tree-group g (lane>>5); wave owns 32 trees;
// chain i (0..15): step s=i>>2, c=i&3, t = tb + 8s + 4g + c.
// LDS: xs(66KB) + pt0(16KB) + pt1(64KB) + rt(4KB) = 152 KB, 1 block/CU.

#define BB 32768
#define TT 512
#define FF 512
#define PADW 65536
#define ROWS 32
#define THREADS 1024
#define TPW 32
#define XSS 515

#define PT0_OFF 0
#define PT1_OFF 1024
#define PT2_OFF 5120
#define PT3_OFF 21504
#define N_REC   87040

typedef int i32x4 __attribute__((ext_vector_type(4)));

#define GLOAD16(DST, PTR)                                                     \
    asm volatile("global_load_dwordx4 %0, %1, off"                            \
                 : "=&v"(DST) : "v"((unsigned long long)(PTR)))

__global__ __launch_bounds__(256) void build_tables_kernel(
    const int*   __restrict__ nodes_lv,
    const float* __restrict__ biases_lv,
    const float* __restrict__ leaf_nodes,
    int4*        __restrict__ ws16)
{
    const int i = blockIdx.x * 256 + threadIdx.x;
    if (i >= N_REC) return;

    int l, p, off;
    if (i < PT1_OFF)      { l = 0; off = PT0_OFF; }
    else if (i < PT2_OFF) { l = 2; off = PT1_OFF; }
    else if (i < PT3_OFF) { l = 4; off = PT2_OFF; }
    else {
        p = i - PT3_OFF;
        const int   f  = nodes_lv[6 * PADW + p];
        const float b  = biases_lv[6 * PADW + p];
        const float lL = leaf_nodes[2 * p];
        const float lR = leaf_nodes[2 * p + 1];
        ws16[i] = make_int4(f, __float_as_int(b),
                            __float_as_int(lL), __float_as_int(lR));
        return;
    }
    p = i - off;
    const int   f0 = nodes_lv[l * PADW + p];
    const float b0 = biases_lv[l * PADW + p];
    const int   fL = nodes_lv[(l + 1) * PADW + 2 * p];
    const int   fR = nodes_lv[(l + 1) * PADW + 2 * p + 1];
    const float bL = biases_lv[(l + 1) * PADW + 2 * p];
    const float bR = biases_lv[(l + 1) * PADW + 2 * p + 1];
    ws16[i] = make_int4(f0 | (fL << 10) | (fR << 20), __float_as_int(b0),
                        __float_as_int(bL), __float_as_int(bR));
}

// Serial 2-level resolve (works on int4 or i32x4)
#define PAIR_RESOLVE(REC, P)                                                  \
    {                                                                         \
        const int   fp_ = (REC).x;                                            \
        const bool  g0_ = xrow[fp_ & 1023] >= __int_as_float((REC).y);        \
        const int   f1_ = g0_ ? ((fp_ >> 20) & 1023) : ((fp_ >> 10) & 1023);  \
        const float h1_ = g0_ ? __int_as_float((REC).w) : __int_as_float((REC).z); \
        const bool  g1_ = xrow[f1_] >= h1_;                                   \
        (P) = 4 * (P) + 2 * (int)g0_ + (int)g1_;                              \
    }

// LDS levels 0-3 for chain I -> P
#define CHAIN_LDS(I, P)                                                       \
    {                                                                         \
        const int  t_ = tb + 8 * ((I) >> 2) + 4 * g + ((I) & 3);              \
        const int2 rn_ = rt[t_];                                              \
        int p_ = 2 * t_ + (xrow[rn_.x] >= __int_as_float(rn_.y) ? 1 : 0);     \
        const int4 q0_ = pt0[p_];                                             \
        PAIR_RESOLVE(q0_, p_);                                                \
        const int4 q1_ = pt1[p_];                                             \
        PAIR_RESOLVE(q1_, p_);                                                \
        (P) = p_;                                                             \
    }

// Resolve PT3 record to leaf value
#define LEAF(REC) (xrow[(REC).x] >= __int_as_float((REC).y)                   \
                       ? __int_as_float((REC).w) : __int_as_float((REC).z))

__global__ __launch_bounds__(THREADS, 4) void gbdt_walk_kernel(
    const float* __restrict__ x,
    const int*   __restrict__ root_nodes,
    const float* __restrict__ root_biases,
    const int4*  __restrict__ ws16,
    float*       __restrict__ out)
{
    __shared__ float xs[ROWS * XSS];   // 65,920 B
    __shared__ int4  pt0[1024];        // 16,384 B
    __shared__ int4  pt1[4096];        // 65,536 B
    __shared__ int2  rt[512];          //  4,096 B  total 151,936 B

    const int tid = threadIdx.x;
    const int b0  = blockIdx.x * ROWS;

    const float4* __restrict__ xr = (const float4*)(x + (size_t)b0 * FF);
    #pragma unroll
    for (int i = 0; i < (ROWS * FF / 4) / THREADS; ++i) {
        int fidx = i * THREADS + tid;
        int r = fidx >> 7, c4 = fidx & 127;
        float4 v = xr[fidx];
        float* d = &xs[r * XSS + (c4 << 2)];
        d[0] = v.x; d[1] = v.y; d[2] = v.z; d[3] = v.w;
    }
    #pragma unroll
    for (int i = 0; i < 5; ++i) {
        int idx = i * THREADS + tid;
        if (idx < 5120) {
            int4 v = ws16[idx];
            if (idx < 1024) pt0[idx] = v;
            else            pt1[idx - 1024] = v;
        }
    }
    if (tid < 512)
        rt[tid] = make_int2(root_nodes[tid], __float_as_int(root_biases[tid]));
    __syncthreads();

    const int wv   = tid >> 6;
    const int lane = tid & 63;
    const int row  = lane & 31;
    const int g    = lane >> 5;
    const int tb   = wv * TPW;
    const float* __restrict__ xrow = &xs[row * XSS];
    float* __restrict__ orow = out + (size_t)(b0 + row) * TT;

    int p0,p1,p2,p3,p4_,p5,p6,p7,p8,p9,p10,p11,p12,p13,p14,p15;
    i32x4 ra0,ra1,ra2,ra3,ra4,ra5,ra6,ra7;
    i32x4 rb0,rb1,rb2,rb3,rb4,rb5,rb6,rb7;
    i32x4 la0,la1,la2,la3,la4,la5,la6,la7;
    i32x4 lb0,lb1,lb2,lb3,lb4,lb5,lb6,lb7;

    // ---- batch A pass1: LDS levels 0-3, issue PT2 ----
    CHAIN_LDS(0,  p0 ); GLOAD16(ra0, ws16 + PT2_OFF + p0 );
    CHAIN_LDS(1,  p1 ); GLOAD16(ra1, ws16 + PT2_OFF + p1 );
    CHAIN_LDS(2,  p2 ); GLOAD16(ra2, ws16 + PT2_OFF + p2 );
    CHAIN_LDS(3,  p3 ); GLOAD16(ra3, ws16 + PT2_OFF + p3 );
    CHAIN_LDS(4,  p4_); GLOAD16(ra4, ws16 + PT2_OFF + p4_);
    CHAIN_LDS(5,  p5 ); GLOAD16(ra5, ws16 + PT2_OFF + p5 );
    CHAIN_LDS(6,  p6 ); GLOAD16(ra6, ws16 + PT2_OFF + p6 );
    CHAIN_LDS(7,  p7 ); GLOAD16(ra7, ws16 + PT2_OFF + p7 );
    // ---- batch B pass1 (hides A's PT2 latency) ----
    CHAIN_LDS(8,  p8 ); GLOAD16(rb0, ws16 + PT2_OFF + p8 );
    CHAIN_LDS(9,  p9 ); GLOAD16(rb1, ws16 + PT2_OFF + p9 );
    CHAIN_LDS(10, p10); GLOAD16(rb2, ws16 + PT2_OFF + p10);
    CHAIN_LDS(11, p11); GLOAD16(rb3, ws16 + PT2_OFF + p11);
    CHAIN_LDS(12, p12); GLOAD16(rb4, ws16 + PT2_OFF + p12);
    CHAIN_LDS(13, p13); GLOAD16(rb5, ws16 + PT2_OFF + p13);
    CHAIN_LDS(14, p14); GLOAD16(rb6, ws16 + PT2_OFF + p14);
    CHAIN_LDS(15, p15); GLOAD16(rb7, ws16 + PT2_OFF + p15);

    asm volatile("s_waitcnt vmcnt(8)" ::: "memory");   // A.PT2 done
    __builtin_amdgcn_sched_barrier(0);

    // ---- A pass2: resolve PT2, issue PT3 ----
    PAIR_RESOLVE(ra0, p0 ); GLOAD16(la0, ws16 + PT3_OFF + p0 );
    PAIR_RESOLVE(ra1, p1 ); GLOAD16(la1, ws16 + PT3_OFF + p1 );
    PAIR_RESOLVE(ra2, p2 ); GLOAD16(la2, ws16 + PT3_OFF + p2 );
    PAIR_RESOLVE(ra3, p3 ); GLOAD16(la3, ws16 + PT3_OFF + p3 );
    PAIR_RESOLVE(ra4, p4_); GLOAD16(la4, ws16 + PT3_OFF + p4_);
    PAIR_RESOLVE(ra5, p5 ); GLOAD16(la5, ws16 + PT3_OFF + p5 );
    PAIR_RESOLVE(ra6, p6 ); GLOAD16(la6, ws16 + PT3_OFF + p6 );
    PAIR_RESOLVE(ra7, p7 ); GLOAD16(la7, ws16 + PT3_OFF + p7 );

    asm volatile("s_waitcnt vmcnt(8)" ::: "memory");   // B.PT2 done
    __builtin_amdgcn_sched_barrier(0);

    // ---- B pass2 ----
    PAIR_RESOLVE(rb0, p8 ); GLOAD16(lb0, ws16 + PT3_OFF + p8 );
    PAIR_RESOLVE(rb1, p9 ); GLOAD16(lb1, ws16 + PT3_OFF + p9 );
    PAIR_RESOLVE(rb2, p10); GLOAD16(lb2, ws16 + PT3_OFF + p10);
    PAIR_RESOLVE(rb3, p11); GLOAD16(lb3, ws16 + PT3_OFF + p11);
    PAIR_RESOLVE(rb4, p12); GLOAD16(lb4, ws16 + PT3_OFF + p12);
    PAIR_RESOLVE(rb5, p13); GLOAD16(lb5, ws16 + PT3_OFF + p13);
    PAIR_RESOLVE(rb6, p14); GLOAD16(lb6, ws16 + PT3_OFF + p14);
    PAIR_RESOLVE(rb7, p15); GLOAD16(lb7, ws16 + PT3_OFF + p15);

    asm volatile("s_waitcnt vmcnt(8)" ::: "memory");   // A.PT3 done
    __builtin_amdgcn_sched_barrier(0);

    // ---- A pass3: leaves for steps 0,1 ----
    {
        float v0 = LEAF(la0), v1 = LEAF(la1), v2 = LEAF(la2), v3 = LEAF(la3);
        *(float4*)&orow[tb + 4 * g]     = make_float4(v0, v1, v2, v3);
        float w0 = LEAF(la4), w1 = LEAF(la5), w2 = LEAF(la6), w3 = LEAF(la7);
        *(float4*)&orow[tb + 8 + 4 * g] = make_float4(w0, w1, w2, w3);
    }

    asm volatile("s_waitcnt vmcnt(2)" ::: "memory");   // B.PT3 done (2 stores out)
    __builtin_amdgcn_sched_barrier(0);

    // ---- B pass3: leaves for steps 2,3 ----
    {
        float v0 = LEAF(lb0), v1 = LEAF(lb1), v2 = LEAF(lb2), v3 = LEAF(lb3);
        *(float4*)&orow[tb + 16 + 4 * g] = make_float4(v0, v1, v2, v3);
        float w0 = LEAF(lb4), w1 = LEAF(lb5), w2 = LEAF(lb6), w3 = LEAF(lb7);
        *(float4*)&orow[tb + 24 + 4 * g] = make_float4(w0, w1, w2, w3);
    }
}

// Fallback (ws too small): direct gathers from the original tables.
__global__ __launch_bounds__(THREADS) void gbdt_walk_fallback(
    const float* __restrict__ x,
    const int*   __restrict__ root_nodes,
    const float* __restrict__ root_biases,
    const int*   __restrict__ nodes_lv,
    const float* __restrict__ biases_lv,
    const float* __restrict__ leaf_nodes,
    float*       __restrict__ out)
{
    __shared__ float xs[ROWS * XSS];
    const int tid = threadIdx.x;
    const int b0  = blockIdx.x * ROWS;
    const float4* __restrict__ xr = (const float4*)(x + (size_t)b0 * FF);
    #pragma unroll
    for (int i = 0; i < (ROWS * FF / 4) / THREADS; ++i) {
        int fidx = i * THREADS + tid;
        int r = fidx >> 7, c4 = fidx & 127;
        float4 v = xr[fidx];
        float* d = &xs[r * XSS + (c4 << 2)];
        d[0] = v.x; d[1] = v.y; d[2] = v.z; d[3] = v.w;
    }
    __syncthreads();
    const int wv   = tid >> 6;
    const int lane = tid & 63;
    const int row  = lane & 31;
    const int g    = lane >> 5;
    const int tb   = wv * TPW;
    const float* __restrict__ xrow = &xs[row * XSS];
    float* __restrict__ orow = out + (size_t)(b0 + row) * TT;
    #pragma unroll
    for (int s = 0; s < TPW / 2; ++s) {
        const int t = tb + 2 * s + g;
        int p = 2 * t + (xrow[root_nodes[t]] >= root_biases[t] ? 1 : 0);
        #pragma unroll
        for (int l = 0; l < 7; ++l) {
            const int   f = nodes_lv[l * PADW + p];
            const float h = biases_lv[l * PADW + p];
            p = 2 * p + (xrow[f] >= h ? 1 : 0);
        }
        orow[t] = leaf_nodes[p];
    }
}

extern "C" void kernel_launch(void* const* d_in, const int* in_sizes, int n_in,
                              void* d_out, int out_size, void* d_ws, size_t ws_size,
                              hipStream_t stream) {
    const float* x            = (const float*)d_in[0];
    const int*   root_nodes   = (const int*)  d_in[1];
    const float* root_biases  = (const float*)d_in[2];
    const int*   nodes_lv     = (const int*)  d_in[4];
    const float* biases_lv    = (const float*)d_in[5];
    const float* leaf_nodes   = (const float*)d_in[6];
    float*       out          = (float*)d_out;

    dim3 grid(BB / ROWS);   // 1024 blocks
    dim3 block(THREADS);

    if (ws_size >= (size_t)N_REC * 16) {
        int4* ws16 = (int4*)d_ws;
        build_tables_kernel<<<(N_REC + 255) / 256, 256, 0, stream>>>(
            nodes_lv, biases_lv, leaf_nodes, ws16);
        gbdt_walk_kernel<<<grid, block, 0, stream>>>(
            x, root_nodes, root_biases, ws16, out);
    } else {
        gbdt_walk_fallback<<<grid, block, 0, stream>>>(
            x, root_nodes, root_biases, nodes_lv, biases_lv, leaf_nodes, out);
    }
}

// Round 19
// 68.781 us; speedup vs baseline: 1.0578x; 1.0490x over previous
//
#include <hip/hip_runtime.h>

// GBDT ensemble inference — R19: R13 (best, 68.5us) + per-wave PHASE STAGGER.
// After the staging barrier all 16 waves were phase-locked (identical
// instruction stream) -> LDS/VMEM/VALU phases never overlap across waves.
// Rotate each wave's step order by r=(wv&3)^((wv>>2)&3) so co-resident waves
// are at different pipeline phases. Zero extra work.
// B=32768, T=512, D=8, F=512, C=1.
//
// ws16 layout (int4 records):
//   PT0 [0,1024):      levels 0,1   (staged to LDS)
//   PT1 [1024,5120):   levels 2,3   (staged to LDS)
//   PT2 [5120,21504):  levels 4,5   (VMEM)
//   PT3 [21504,87040): level 6+leaf (VMEM)
// Pair rec: {f0|fL<<10|fR<<20, b0, bL, bR}; PT3 rec: {f6, b6, leafL, leafR}.
//
// Mapping: lane = row (0..31) + tree-group g (lane>>5); wave owns 32 trees;
// per step 8 trees, lane handles 4 consecutive; float4 leaf stores.
// LDS: xs(66KB) + pt0(16KB) + pt1(64KB) + rt(4KB) = 152 KB, 1 block/CU.

#define BB 32768
#define TT 512
#define FF 512
#define PADW 65536
#define ROWS 32
#define THREADS 1024
#define TPW 32
#define XSS 515           // odd stride: correlated-feature lanes spread banks

#define PT0_OFF 0
#define PT1_OFF 1024
#define PT2_OFF 5120
#define PT3_OFF 21504
#define N_REC   87040

__global__ __launch_bounds__(256) void build_tables_kernel(
    const int*   __restrict__ nodes_lv,
    const float* __restrict__ biases_lv,
    const float* __restrict__ leaf_nodes,
    int4*        __restrict__ ws16)
{
    const int i = blockIdx.x * 256 + threadIdx.x;
    if (i >= N_REC) return;

    int l, p, off;
    if (i < PT1_OFF)      { l = 0; off = PT0_OFF; }
    else if (i < PT2_OFF) { l = 2; off = PT1_OFF; }
    else if (i < PT3_OFF) { l = 4; off = PT2_OFF; }
    else {
        p = i - PT3_OFF;
        const int   f  = nodes_lv[6 * PADW + p];
        const float b  = biases_lv[6 * PADW + p];
        const float lL = leaf_nodes[2 * p];
        const float lR = leaf_nodes[2 * p + 1];
        ws16[i] = make_int4(f, __float_as_int(b),
                            __float_as_int(lL), __float_as_int(lR));
        return;
    }
    p = i - off;
    const int   f0 = nodes_lv[l * PADW + p];
    const float b0 = biases_lv[l * PADW + p];
    const int   fL = nodes_lv[(l + 1) * PADW + 2 * p];
    const int   fR = nodes_lv[(l + 1) * PADW + 2 * p + 1];
    const float bL = biases_lv[(l + 1) * PADW + 2 * p];
    const float bR = biases_lv[(l + 1) * PADW + 2 * p + 1];
    ws16[i] = make_int4(f0 | (fL << 10) | (fR << 20), __float_as_int(b0),
                        __float_as_int(bL), __float_as_int(bR));
}

// Serial 2-level resolve
#define PAIR_RESOLVE(REC, P)                                                  \
    {                                                                         \
        const int   fp = (REC).x;                                             \
        const bool  g0 = xrow[fp & 1023] >= __int_as_float((REC).y);          \
        const int   f1 = g0 ? ((fp >> 20) & 1023) : ((fp >> 10) & 1023);      \
        const float h1 = g0 ? __int_as_float((REC).w) : __int_as_float((REC).z); \
        const bool  g1 = xrow[f1] >= h1;                                      \
        (P) = 4 * (P) + 2 * (int)g0 + (int)g1;                                \
    }

__global__ __launch_bounds__(THREADS) void gbdt_walk_kernel(
    const float* __restrict__ x,
    const int*   __restrict__ root_nodes,
    const float* __restrict__ root_biases,
    const int4*  __restrict__ ws16,
    float*       __restrict__ out)
{
    __shared__ float xs[ROWS * XSS];   // 65,920 B
    __shared__ int4  pt0[1024];        // 16,384 B (levels 0,1)
    __shared__ int4  pt1[4096];        // 65,536 B (levels 2,3)
    __shared__ int2  rt[512];          //  4,096 B (root f,b)   total 151,936 B

    const int tid = threadIdx.x;
    const int b0  = blockIdx.x * ROWS;

    // ---- stage x rows (coalesced float4) ----
    const float4* __restrict__ xr = (const float4*)(x + (size_t)b0 * FF);
    #pragma unroll
    for (int i = 0; i < (ROWS * FF / 4) / THREADS; ++i) {   // 4 iters
        int fidx = i * THREADS + tid;
        int r = fidx >> 7, c4 = fidx & 127;
        float4 v = xr[fidx];
        float* d = &xs[r * XSS + (c4 << 2)];
        d[0] = v.x; d[1] = v.y; d[2] = v.z; d[3] = v.w;
    }
    // ---- stage PT0+PT1 (5120 int4, coalesced) ----
    #pragma unroll
    for (int i = 0; i < 5; ++i) {
        int idx = i * THREADS + tid;
        if (idx < 5120) {
            int4 v = ws16[idx];
            if (idx < 1024) pt0[idx] = v;
            else            pt1[idx - 1024] = v;
        }
    }
    // ---- stage roots ----
    if (tid < 512)
        rt[tid] = make_int2(root_nodes[tid], __float_as_int(root_biases[tid]));
    __syncthreads();

    const int wv   = tid >> 6;              // wave 0..15
    const int lane = tid & 63;
    const int row  = lane & 31;
    const int g    = lane >> 5;
    const int tb   = wv * TPW;
    const int rot  = (wv & 3) ^ ((wv >> 2) & 3);   // phase stagger
    const float* __restrict__ xrow = &xs[row * XSS];
    float* __restrict__ orow = out + (size_t)(b0 + row) * TT;

    #pragma unroll
    for (int s = 0; s < TPW / 8; ++s) {     // 4 steps, 8 trees each (rotated)
        const int sr = (s + rot) & 3;
        const int tbase = tb + 8 * sr + 4 * g;
        int p[4];

        // ---- LDS macro-stage A: root + PT0 (levels 0,1) ----
        #pragma unroll
        for (int c = 0; c < 4; ++c) {
            const int t = tbase + c;
            const int2 rn = rt[t];
            const bool rb = xrow[rn.x] >= __int_as_float(rn.y);
            p[c] = 2 * t + (int)rb;
        }
        {
            int4 r0[4];
            #pragma unroll
            for (int c = 0; c < 4; ++c) r0[c] = pt0[p[c]];
            #pragma unroll
            for (int c = 0; c < 4; ++c) PAIR_RESOLVE(r0[c], p[c]);
        }
        // ---- LDS macro-stage B: PT1 (levels 2,3) ----
        {
            int4 r1[4];
            #pragma unroll
            for (int c = 0; c < 4; ++c) r1[c] = pt1[p[c]];
            #pragma unroll
            for (int c = 0; c < 4; ++c) PAIR_RESOLVE(r1[c], p[c]);
        }
        // ---- VMEM stage: PT2 (levels 4,5) ----
        {
            int4 r2[4];
            #pragma unroll
            for (int c = 0; c < 4; ++c) r2[c] = ws16[PT2_OFF + p[c]];
            #pragma unroll
            for (int c = 0; c < 4; ++c) PAIR_RESOLVE(r2[c], p[c]);
        }
        // ---- VMEM stage: PT3 (level 6 + leaf) ----
        int4 r3[4];
        #pragma unroll
        for (int c = 0; c < 4; ++c) r3[c] = ws16[PT3_OFF + p[c]];
        float v[4];
        #pragma unroll
        for (int c = 0; c < 4; ++c) {
            const bool gg = xrow[r3[c].x] >= __int_as_float(r3[c].y);
            v[c] = gg ? __int_as_float(r3[c].w) : __int_as_float(r3[c].z);
        }
        *(float4*)&orow[tbase] = make_float4(v[0], v[1], v[2], v[3]);
    }
}

// Fallback (ws too small): direct gathers from the original tables.
__global__ __launch_bounds__(THREADS) void gbdt_walk_fallback(
    const float* __restrict__ x,
    const int*   __restrict__ root_nodes,
    const float* __restrict__ root_biases,
    const int*   __restrict__ nodes_lv,
    const float* __restrict__ biases_lv,
    const float* __restrict__ leaf_nodes,
    float*       __restrict__ out)
{
    __shared__ float xs[ROWS * XSS];
    const int tid = threadIdx.x;
    const int b0  = blockIdx.x * ROWS;
    const float4* __restrict__ xr = (const float4*)(x + (size_t)b0 * FF);
    #pragma unroll
    for (int i = 0; i < (ROWS * FF / 4) / THREADS; ++i) {
        int fidx = i * THREADS + tid;
        int r = fidx >> 7, c4 = fidx & 127;
        float4 v = xr[fidx];
        float* d = &xs[r * XSS + (c4 << 2)];
        d[0] = v.x; d[1] = v.y; d[2] = v.z; d[3] = v.w;
    }
    __syncthreads();
    const int wv   = tid >> 6;
    const int lane = tid & 63;
    const int row  = lane & 31;
    const int g    = lane >> 5;
    const int tb   = wv * TPW;
    const float* __restrict__ xrow = &xs[row * XSS];
    float* __restrict__ orow = out + (size_t)(b0 + row) * TT;
    #pragma unroll
    for (int s = 0; s < TPW / 2; ++s) {
        const int t = tb + 2 * s + g;
        int p = 2 * t + (xrow[root_nodes[t]] >= root_biases[t] ? 1 : 0);
        #pragma unroll
        for (int l = 0; l < 7; ++l) {
            const int   f = nodes_lv[l * PADW + p];
            const float h = biases_lv[l * PADW + p];
            p = 2 * p + (xrow[f] >= h ? 1 : 0);
        }
        orow[t] = leaf_nodes[p];
    }
}

extern "C" void kernel_launch(void* const* d_in, const int* in_sizes, int n_in,
                              void* d_out, int out_size, void* d_ws, size_t ws_size,
                              hipStream_t stream) {
    const float* x            = (const float*)d_in[0];
    const int*   root_nodes   = (const int*)  d_in[1];
    const float* root_biases  = (const float*)d_in[2];
    const int*   nodes_lv     = (const int*)  d_in[4];
    const float* biases_lv    = (const float*)d_in[5];
    const float* leaf_nodes   = (const float*)d_in[6];
    float*       out          = (float*)d_out;

    dim3 grid(BB / ROWS);   // 1024 blocks
    dim3 block(THREADS);

    if (ws_size >= (size_t)N_REC * 16) {
        int4* ws16 = (int4*)d_ws;
        build_tables_kernel<<<(N_REC + 255) / 256, 256, 0, stream>>>(
            nodes_lv, biases_lv, leaf_nodes, ws16);
        gbdt_walk_kernel<<<grid, block, 0, stream>>>(
            x, root_nodes, root_biases, ws16, out);
    } else {
        gbdt_walk_fallback<<<grid, block, 0, stream>>>(
            x, root_nodes, root_biases, nodes_lv, biases_lv, leaf_nodes, out);
    }
}